// Round 7
// baseline (488.688 us; speedup 1.0000x reference)
//
#include <hip/hip_runtime.h>
#include <hip/hip_bf16.h>

// GCN: 3x GCNConv(relu) -> mean over layers -> global mean pool -> linear -> softmax
// N=100000, E=3200000, F_IN=128, F_HID=64, F_OUT=10, G=1000.
//
// out[dst] = dinv[dst] * ( sum_{e: row[e]=dst} z[col[e]] + z[dst] ) + b,
// z = (x @ W) * dinv[:,None], dinv = rsqrt(deg_col + 1).
//
// R7 changes: (1) build_csr sorts each dst's adjacency by source SLICE
// (col>>14, 8 slices x ~3.2MB of Z) -> all waves walk slices in phase, so the
// instantaneous gather working set fits per-XCD L2 (was 12.8MB random ->
// 41% L2 miss, 168MB FETCH per aggregate); (2) aggregate at 1024 threads
// (16 waves/block) for ~full occupancy. Hardening clamps from R6 retained.

#define ALIGN_UP(x, a) (((x) + (a) - 1) / (a) * (a))
#define NBMAX 512        // max buckets (node id >> 8), supports n <= 131072
#define BCAP  10240      // entries per bucket region (mean 8192, +22 sigma)
#define SLICE_SHIFT 14   // source slice = col >> 14 (0..7 for n <= 131072)

__device__ __forceinline__ float bf16_to_f32(ushort u) {
    return __uint_as_float(((unsigned)u) << 16);
}
__device__ __forceinline__ unsigned pack_bf16(float a, float b) {
    union { __hip_bfloat16 h; ushort u; } ua, ub;
    ua.h = __float2bfloat16(a); ub.h = __float2bfloat16(b);
    return (unsigned)ua.u | ((unsigned)ub.u << 16);
}

// ---------------- Pass A: bin edges; RB=(col<<8)|(row&255) uint, CB=col&255 uchar ----------------
__global__ __launch_bounds__(1024) void bin_edges(const int* __restrict__ row,
                                                  const int* __restrict__ col, int E, int NB,
                                                  int* __restrict__ fillR, int* __restrict__ fillC,
                                                  unsigned int* __restrict__ RB,
                                                  unsigned char* __restrict__ CB) {
    __shared__ int cR[NBMAX], cC[NBMAX], bR[NBMAX], bC[NBMAX];
    int t = threadIdx.x;
    for (int i = t; i < NB; i += 1024) { cR[i] = 0; cC[i] = 0; }
    __syncthreads();
    int per = (E + gridDim.x - 1) / gridDim.x;
    int e0 = blockIdx.x * per, e1 = min(E, e0 + per);
    for (int e = e0 + t; e < e1; e += 1024) {
        atomicAdd(&cR[row[e] >> 8], 1);
        atomicAdd(&cC[col[e] >> 8], 1);
    }
    __syncthreads();
    int stag = (int)((blockIdx.x * 37u) % (unsigned)NB);
    for (int j = t; j < NB; j += 1024) {
        int i = j + stag; if (i >= NB) i -= NB;
        bR[i] = cR[i] ? atomicAdd(&fillR[i], cR[i]) : 0;
        bC[i] = cC[i] ? atomicAdd(&fillC[i], cC[i]) : 0;
    }
    __syncthreads();
    for (int i = t; i < NB; i += 1024) { cR[i] = 0; cC[i] = 0; }
    __syncthreads();
    for (int e = e0 + t; e < e1; e += 1024) {    // chunk is L2-hot on re-read
        int r = row[e], c = col[e];
        int br = r >> 8, bc = c >> 8;
        int pR = bR[br] + atomicAdd(&cR[br], 1);
        if (pR < BCAP) RB[(size_t)br * BCAP + pR] = ((unsigned)c << 8) | ((unsigned)r & 255u);
        int pC = bC[bc] + atomicAdd(&cC[bc], 1);
        if (pC < BCAP) CB[(size_t)bc * BCAP + pC] = (unsigned char)(c & 255);
    }
}

// ---------------- Pass B: per-bucket CSR build (dst-major, slice-minor) + dinv ----------------
__global__ __launch_bounds__(1024) void build_csr(const unsigned int* __restrict__ RB,
                                                  const unsigned char* __restrict__ CB,
                                                  const int* __restrict__ fillR,
                                                  const int* __restrict__ fillC,
                                                  int* __restrict__ rowptr, int* __restrict__ indeg,
                                                  float* __restrict__ dinv, int* __restrict__ csr,
                                                  int n, int NB, int E) {
    __shared__ int cnt[2048], start[2048], bump[2048];   // key = (local_dst<<3)|slice
    __shared__ int wsum[16];
    __shared__ int s_base;
    int b = blockIdx.x, t = threadIdx.x;
    int node0 = b << 8;

    // inline exclusive prefix of bucket totals (wave 0)
    if (t < 64) {
        int pre = 0;
        for (int j = t; j < b; j += 64) pre += min(fillR[j], BCAP);
        #pragma unroll
        for (int off = 32; off; off >>= 1) pre += __shfl_down(pre, off, 64);
        if (t == 0) s_base = pre;
    }
    for (int i = t; i < 2048; i += 1024) { cnt[i] = 0; bump[i] = 0; }
    __syncthreads();

    int m = min(fillR[b], BCAP);
    const unsigned int* src = RB + (size_t)b * BCAP;
    for (int i = t; i < m; i += 1024) {
        unsigned en = src[i];
        int key = (((int)(en & 255u)) << 3) | ((int)(en >> 8) >> SLICE_SHIFT);
        atomicAdd(&cnt[key], 1);
    }
    __syncthreads();

    // block exclusive scan over 2048 counters (each thread owns pair 2t,2t+1)
    int v0 = cnt[2 * t], v1 = cnt[2 * t + 1];
    int pair = v0 + v1;
    int lane = t & 63, w = t >> 6;
    int x = pair;
    #pragma unroll
    for (int off = 1; off < 64; off <<= 1) {
        int y = __shfl_up(x, off, 64);
        if (lane >= off) x += y;
    }
    if (lane == 63) wsum[w] = x;
    __syncthreads();
    int wb = 0;
    #pragma unroll
    for (int i = 0; i < 16; i++) if (i < w) wb += wsum[i];
    int excl = wb + x - pair;
    start[2 * t] = excl;
    start[2 * t + 1] = excl + v0;
    __syncthreads();

    int base = s_base;
    if (t < 256) {
        int v = node0 + t;
        if (v < n) {
            int s0 = start[t << 3];
            int s1 = (t < 255) ? start[(t + 1) << 3] : m;
            rowptr[v] = base + s0;
            indeg[v]  = s1 - s0;
        }
    }
    __syncthreads();
    for (int i = t; i < m; i += 1024) {
        unsigned en = src[i];
        int local = (int)(en & 255u);
        int c = (int)(en >> 8);
        int key = (local << 3) | (c >> SLICE_SHIFT);
        int pos = base + start[key] + atomicAdd(&bump[key], 1);
        if (pos < E) csr[pos] = c;                 // hardening: never write OOB
    }
    // col-side histogram -> dinv (reuse cnt[0..255])
    __syncthreads();
    if (t < 256) cnt[t] = 0;
    __syncthreads();
    int mc = min(fillC[b], BCAP);
    const unsigned char* sc = CB + (size_t)b * BCAP;
    for (int i = t; i < mc; i += 1024)
        atomicAdd(&cnt[(int)sc[i]], 1);
    __syncthreads();
    int v = node0 + t;
    if (t < 256 && v < n) dinv[v] = rsqrtf((float)(cnt[t] + 1));
}

// ---------------- dense: Z(bf16) = (X @ W) * dinv[:,None] ----------------
// Block = 64 nodes x 64 outputs. lane = node; wave w owns outputs [16w,16w+16).
// W rows are wave-uniform -> scalar s_load.
template <int K>
__global__ __launch_bounds__(256) void gemm_scale(const float* __restrict__ X,
                                                  const float* __restrict__ W,
                                                  const float* __restrict__ dinv,
                                                  unsigned* __restrict__ Z, int n) {
    constexpr int KP = K + 4;
    __shared__ __align__(16) float xs[64 * KP];
    int v0 = blockIdx.x * 64;
    int t = threadIdx.x;

    constexpr int C4 = K / 4;
    for (int idx = t; idx < 64 * C4; idx += 256) {
        int i = idx / C4, c = idx % C4;
        int v = v0 + i;
        float4 val = (v < n) ? ((const float4*)(X + (size_t)v * K))[c]
                             : make_float4(0.f, 0.f, 0.f, 0.f);
        *(float4*)&xs[i * KP + c * 4] = val;
    }
    __syncthreads();

    int lane = t & 63;
    int wave = __builtin_amdgcn_readfirstlane(t >> 6);
    int j0 = wave * 16;
    float acc[16];
    #pragma unroll
    for (int jj = 0; jj < 16; jj++) acc[jj] = 0.f;

    const float* xrow = &xs[lane * KP];
    #pragma unroll 2
    for (int k = 0; k < K; k += 4) {
        float4 xv = *(const float4*)&xrow[k];
        #pragma unroll
        for (int kk = 0; kk < 4; kk++) {
            float xk = (&xv.x)[kk];
            const float* wrow = W + (k + kk) * 64 + j0;   // wave-uniform -> s_load
            #pragma unroll
            for (int jj = 0; jj < 16; jj++)
                acc[jj] = fmaf(xk, wrow[jj], acc[jj]);
        }
    }

    float dv = (v0 + lane < n) ? dinv[v0 + lane] : 0.f;
    __syncthreads();
    // transpose via LDS (reuse xs) with rotate swizzle; store coalesced bf16 rows
    unsigned* zs32 = (unsigned*)xs;                // 64 nodes x 32 uints (2 bf16 each)
    #pragma unroll
    for (int p = 0; p < 8; p++) {
        int pl = (j0 >> 1) + p;                    // logical uint column
        int phys = (pl + lane) & 31;
        zs32[lane * 32 + phys] = pack_bf16(acc[2 * p] * dv, acc[2 * p + 1] * dv);
    }
    __syncthreads();
    for (int idx = t; idx < 2048; idx += 256) {
        int i = idx >> 5, c = idx & 31;
        int v = v0 + i;
        if (v < n) Z[(size_t)v * 32 + c] = zs32[i * 32 + ((c + i) & 31)];
    }
}

// ---------------- sparse aggregate + bias + relu (bf16 gather, full width) ----------------
// One wave per dst node; 64 lanes x 2B = one 128B line per edge. 16 waves/block.
__global__ __launch_bounds__(1024) void aggregate(const ushort* __restrict__ Z,
                                                  const int* __restrict__ rowptr,
                                                  const int* __restrict__ indeg,
                                                  const int* __restrict__ csr,
                                                  const float* __restrict__ dinv,
                                                  const float* __restrict__ bias,
                                                  float* __restrict__ Xout, int n) {
    int wave = threadIdx.x >> 6;
    int lane = threadIdx.x & 63;
    int v = blockIdx.x * 16 + wave;
    if (v >= n) return;
    int vs = __builtin_amdgcn_readfirstlane(v);
    int nm1 = n - 1;

    float acc = bf16_to_f32(Z[(size_t)vs * 64 + lane]);   // self-loop
    int s = rowptr[vs], c = indeg[vs];
    int i = 0;
    for (; i + 7 < c; i += 8) {
        int idx[8];
        #pragma unroll
        for (int u = 0; u < 8; u++) idx[u] = min(csr[s + i + u], nm1);  // hardening clamp
        float a[8];
        #pragma unroll
        for (int u = 0; u < 8; u++) a[u] = bf16_to_f32(Z[(size_t)idx[u] * 64 + lane]);
        acc += ((a[0] + a[1]) + (a[2] + a[3])) + ((a[4] + a[5]) + (a[6] + a[7]));
    }
    for (; i + 1 < c; i += 2) {
        int s0 = min(csr[s + i], nm1), s1 = min(csr[s + i + 1], nm1);
        acc += bf16_to_f32(Z[(size_t)s0 * 64 + lane]) + bf16_to_f32(Z[(size_t)s1 * 64 + lane]);
    }
    if (i < c) acc += bf16_to_f32(Z[(size_t)min(csr[s + i], nm1) * 64 + lane]);

    float val = fmaxf(acc * dinv[vs] + bias[lane], 0.f);
    Xout[(size_t)vs * 64 + lane] = val;
}

// ---------------- fused pool (block per graph, batch sorted) + linear + softmax ----------------
__device__ __forceinline__ int lbound(const int* a, int n, int key) {
    int lo = 0, hi = n;
    while (lo < hi) { int mid = (lo + hi) >> 1; if (a[mid] < key) lo = mid + 1; else hi = mid; }
    return lo;
}

__global__ __launch_bounds__(256) void pool_head(const float* __restrict__ x1,
                                                 const float* __restrict__ x2,
                                                 const float* __restrict__ x3,
                                                 const int* __restrict__ batch,
                                                 const float* __restrict__ Wl,
                                                 const float* __restrict__ bl,
                                                 float* __restrict__ out, int n) {
    __shared__ int sb[2];
    __shared__ float red[4][64];
    __shared__ float ps[64];
    __shared__ float lg[10];
    int g = blockIdx.x, t = threadIdx.x;
    int wave = t >> 6, lane = t & 63;
    if (t < 2) sb[t] = lbound(batch, n, g + t);
    __syncthreads();
    int s0 = sb[0], s1 = sb[1];
    float acc = 0.f;
    for (int v = s0 + wave; v < s1; v += 4)
        acc += x1[(size_t)v * 64 + lane] + x2[(size_t)v * 64 + lane] + x3[(size_t)v * 64 + lane];
    red[wave][lane] = acc;
    __syncthreads();
    if (t < 64) {
        int c = s1 - s0;
        float denom = 3.0f * (float)(c > 1 ? c : 1);
        ps[t] = (red[0][t] + red[1][t] + red[2][t] + red[3][t]) / denom;
    }
    __syncthreads();
    if (t < 10) {
        float a = bl[t];
        #pragma unroll 8
        for (int f = 0; f < 64; f++) a += ps[f] * Wl[f * 10 + t];
        lg[t] = a;
    }
    __syncthreads();
    if (t < 10) {
        float mx = -1e30f;
        for (int j = 0; j < 10; j++) mx = fmaxf(mx, lg[j]);
        float e = expf(lg[t] - mx);
        float ss = 0.f;
        for (int j = 0; j < 10; j++) ss += expf(lg[j] - mx);
        out[g * 10 + t] = e / ss;
    }
}

extern "C" void kernel_launch(void* const* d_in, const int* in_sizes, int n_in,
                              void* d_out, int out_size, void* d_ws, size_t ws_size,
                              hipStream_t stream) {
    const float* feats = (const float*)d_in[0];
    const int*   eidx  = (const int*)d_in[1];
    const int*   batch = (const int*)d_in[2];
    const float* W1 = (const float*)d_in[4];
    const float* b1 = (const float*)d_in[5];
    const float* W2 = (const float*)d_in[6];
    const float* b2 = (const float*)d_in[7];
    const float* W3 = (const float*)d_in[8];
    const float* b3 = (const float*)d_in[9];
    const float* Wl = (const float*)d_in[10];
    const float* bl = (const float*)d_in[11];
    float* out = (float*)d_out;

    int n = in_sizes[0] / 128;
    int E = in_sizes[1] / 2;
    int G = out_size / 10;
    int NB = ((n - 1) >> 8) + 1;
    const int* row = eidx;       // destination
    const int* col = eidx + E;   // source

    char* ws = (char*)d_ws;
    size_t o = 0;
    size_t o_fill    = o; o += 2 * NBMAX * 4;           // fillR | fillC (zeroed)
    size_t o_rowptr  = o; o += ALIGN_UP((size_t)n * 4, 256);
    size_t o_indeg   = o; o += ALIGN_UP((size_t)n * 4, 256);
    size_t o_dinv    = o; o += ALIGN_UP((size_t)n * 4, 256);
    size_t o_csr     = o; o += ALIGN_UP((size_t)E * 4, 256);
    size_t o_z       = o; o += ALIGN_UP((size_t)n * 64 * 2, 256);   // bf16 Z
    size_t o_union   = o;
    size_t rb_bytes  = (size_t)NBMAX * BCAP * 4;
    size_t xl_bytes  = ALIGN_UP((size_t)n * 64 * 4, 256);
    (void)ws_size; (void)n_in;

    int*   fillR   = (int*)(ws + o_fill);
    int*   fillC   = fillR + NBMAX;
    int*   rowptr  = (int*)(ws + o_rowptr);
    int*   indeg   = (int*)(ws + o_indeg);
    float* dinv    = (float*)(ws + o_dinv);
    int*   csr     = (int*)(ws + o_csr);
    unsigned* z    = (unsigned*)(ws + o_z);
    unsigned int*  RB = (unsigned int*)(ws + o_union);
    unsigned char* CB = (unsigned char*)(ws + o_union + rb_bytes);
    float* x1 = (float*)(ws + o_union);
    float* x2 = (float*)(ws + o_union + xl_bytes);
    float* x3 = (float*)(ws + o_union + 2 * xl_bytes);

    hipMemsetAsync(ws + o_fill, 0, 2 * NBMAX * 4, stream);

    int gridG = (n + 63) / 64;    // gemm: 64 nodes per block
    int gridA = (n + 15) / 16;    // aggregate: 16 waves/block, one node per wave

    bin_edges<<<256, 1024, 0, stream>>>(row, col, E, NB, fillR, fillC, RB, CB);
    build_csr<<<NB, 1024, 0, stream>>>(RB, CB, fillR, fillC,
                                       rowptr, indeg, dinv, csr, n, NB, E);

    // conv1
    gemm_scale<128><<<gridG, 256, 0, stream>>>(feats, W1, dinv, z, n);
    aggregate<<<gridA, 1024, 0, stream>>>((const ushort*)z, rowptr, indeg, csr, dinv, b1, x1, n);
    // conv2
    gemm_scale<64><<<gridG, 256, 0, stream>>>(x1, W2, dinv, z, n);
    aggregate<<<gridA, 1024, 0, stream>>>((const ushort*)z, rowptr, indeg, csr, dinv, b2, x2, n);
    // conv3
    gemm_scale<64><<<gridG, 256, 0, stream>>>(x2, W3, dinv, z, n);
    aggregate<<<gridA, 1024, 0, stream>>>((const ushort*)z, rowptr, indeg, csr, dinv, b3, x3, n);

    pool_head<<<G, 256, 0, stream>>>(x1, x2, x3, batch, Wl, bl, out, n);
}

// Round 8
// 479.901 us; speedup vs baseline: 1.0183x; 1.0183x over previous
//
#include <hip/hip_runtime.h>
#include <hip/hip_bf16.h>

// GCN: 3x GCNConv(relu) -> mean over layers -> global mean pool -> linear -> softmax
// N=100000, E=3200000, F_IN=128, F_HID=64, F_OUT=10, G=1000.
//
// out[dst] = dinv[dst] * ( sum_{e: row[e]=dst} z[col[e]] + z[dst] ) + b,
// z = (x @ W) * dinv[:,None], dinv = rsqrt(deg_col + 1).
//
// R8: (1) revert R7's slice-sort + 1024-thr aggregate (regressed: FETCH
// 168->162MB only, occupancy fell) to the R6 shapes; (2) gemm rebuilt: W
// staged in LDS, per-wave fragment read as broadcast ds_read_b128 (kills the
// s_load-latency stall), x staged k-major with rotate swizzle (all LDS
// accesses <=2-way conflict = free); (3) aggregate edge-unroll 16.

#define ALIGN_UP(x, a) (((x) + (a) - 1) / (a) * (a))
#define NBMAX 512        // max buckets (node id >> 8), supports n <= 131072
#define BCAP  10240      // entries per bucket region (mean 8192, +22 sigma)

__device__ __forceinline__ float bf16_to_f32(ushort u) {
    return __uint_as_float(((unsigned)u) << 16);
}
__device__ __forceinline__ unsigned pack_bf16(float a, float b) {
    union { __hip_bfloat16 h; ushort u; } ua, ub;
    ua.h = __float2bfloat16(a); ub.h = __float2bfloat16(b);
    return (unsigned)ua.u | ((unsigned)ub.u << 16);
}

// ---------------- Pass A: bin edges; RB=(col<<8)|(row&255) uint, CB=col&255 uchar ----------------
__global__ __launch_bounds__(1024) void bin_edges(const int* __restrict__ row,
                                                  const int* __restrict__ col, int E, int NB,
                                                  int* __restrict__ fillR, int* __restrict__ fillC,
                                                  unsigned int* __restrict__ RB,
                                                  unsigned char* __restrict__ CB) {
    __shared__ int cR[NBMAX], cC[NBMAX], bR[NBMAX], bC[NBMAX];
    int t = threadIdx.x;
    for (int i = t; i < NB; i += 1024) { cR[i] = 0; cC[i] = 0; }
    __syncthreads();
    int per = (E + gridDim.x - 1) / gridDim.x;
    int e0 = blockIdx.x * per, e1 = min(E, e0 + per);
    for (int e = e0 + t; e < e1; e += 1024) {
        atomicAdd(&cR[row[e] >> 8], 1);
        atomicAdd(&cC[col[e] >> 8], 1);
    }
    __syncthreads();
    int stag = (int)((blockIdx.x * 37u) % (unsigned)NB);
    for (int j = t; j < NB; j += 1024) {
        int i = j + stag; if (i >= NB) i -= NB;
        bR[i] = cR[i] ? atomicAdd(&fillR[i], cR[i]) : 0;
        bC[i] = cC[i] ? atomicAdd(&fillC[i], cC[i]) : 0;
    }
    __syncthreads();
    for (int i = t; i < NB; i += 1024) { cR[i] = 0; cC[i] = 0; }
    __syncthreads();
    for (int e = e0 + t; e < e1; e += 1024) {    // chunk is L2-hot on re-read
        int r = row[e], c = col[e];
        int br = r >> 8, bc = c >> 8;
        int pR = bR[br] + atomicAdd(&cR[br], 1);
        if (pR < BCAP) RB[(size_t)br * BCAP + pR] = ((unsigned)c << 8) | ((unsigned)r & 255u);
        int pC = bC[bc] + atomicAdd(&cC[bc], 1);
        if (pC < BCAP) CB[(size_t)bc * BCAP + pC] = (unsigned char)(c & 255);
    }
}

// ---------------- Pass B: per-bucket CSR build + col-degree -> dinv ----------------
__global__ __launch_bounds__(1024) void build_csr(const unsigned int* __restrict__ RB,
                                                  const unsigned char* __restrict__ CB,
                                                  const int* __restrict__ fillR,
                                                  const int* __restrict__ fillC,
                                                  int* __restrict__ rowptr, int* __restrict__ indeg,
                                                  float* __restrict__ dinv, int* __restrict__ csr,
                                                  int n, int NB, int E) {
    __shared__ int cnt[256], start[256], bump[256];
    __shared__ int wsum[4];
    __shared__ int s_base;
    int b = blockIdx.x, t = threadIdx.x;
    int node0 = b << 8;

    // inline exclusive prefix of bucket totals (wave 0)
    if (t < 64) {
        int pre = 0;
        for (int j = t; j < b; j += 64) pre += min(fillR[j], BCAP);
        #pragma unroll
        for (int off = 32; off; off >>= 1) pre += __shfl_down(pre, off, 64);
        if (t == 0) s_base = pre;
    }
    if (t < 256) { cnt[t] = 0; bump[t] = 0; }
    __syncthreads();

    int m = min(fillR[b], BCAP);
    const unsigned int* src = RB + (size_t)b * BCAP;
    for (int i = t; i < m; i += 1024)
        atomicAdd(&cnt[src[i] & 255u], 1);
    __syncthreads();

    int my = (t < 256) ? cnt[t] : 0;
    int lane = t & 63, w = (t >> 6) & 3;
    int x = my;
    #pragma unroll
    for (int off = 1; off < 64; off <<= 1) {
        int y = __shfl_up(x, off, 64);
        if (lane >= off) x += y;
    }
    if (t < 256 && lane == 63) wsum[w] = x;
    __syncthreads();
    int base = s_base;
    if (t < 256) {
        int wb = 0;
        #pragma unroll
        for (int i = 0; i < 4; i++) if (i < w) wb += wsum[i];
        int excl = wb + x - my;
        start[t] = excl;
        int v = node0 + t;
        if (v < n) { rowptr[v] = base + excl; indeg[v] = my; }
    }
    __syncthreads();
    for (int i = t; i < m; i += 1024) {
        unsigned en = src[i];
        int local = (int)(en & 255u);
        int c = (int)(en >> 8);
        int pos = base + start[local] + atomicAdd(&bump[local], 1);
        if (pos < E) csr[pos] = c;                 // hardening: never write OOB
    }
    __syncthreads();
    if (t < 256) cnt[t] = 0;
    __syncthreads();
    int mc = min(fillC[b], BCAP);
    const unsigned char* sc = CB + (size_t)b * BCAP;
    for (int i = t; i < mc; i += 1024)
        atomicAdd(&cnt[(int)sc[i]], 1);
    __syncthreads();
    int v = node0 + t;
    if (t < 256 && v < n) dinv[v] = rsqrtf((float)(cnt[t] + 1));
}

// ---------------- dense: Z(bf16) = (X @ W) * dinv[:,None] ----------------
// Block = 64 nodes x 64 outputs, 4 waves; lane = node, wave w owns outputs
// [16w,16w+16). W staged in LDS; fragment reads are same-address broadcast
// ds_read_b128 (no s_load stall). x staged k-major with rotate swizzle:
// staging writes and compute reads are <=2-way bank aliased (free).
template <int K>
__global__ __launch_bounds__(256) void gemm_scale(const float* __restrict__ X,
                                                  const float* __restrict__ W,
                                                  const float* __restrict__ dinv,
                                                  unsigned* __restrict__ Z, int n) {
    __shared__ __align__(16) float Wt[K * 64];        // 32KB (K=128) / 16KB (K=64)
    __shared__ __align__(16) float xs[64 * 64];       // 16KB: one 64-wide K-chunk, k-major
    int v0 = blockIdx.x * 64;
    int t = threadIdx.x;

    // stage W (contiguous copy, fully coalesced / conflict-free)
    for (int idx = t; idx < K * 16; idx += 256)
        ((float4*)Wt)[idx] = ((const float4*)W)[idx];

    int lane = t & 63;
    int wave = __builtin_amdgcn_readfirstlane(t >> 6);
    int j0 = wave * 16;
    float acc[16];
    #pragma unroll
    for (int jj = 0; jj < 16; jj++) acc[jj] = 0.f;
    float dv = (v0 + lane < n) ? dinv[v0 + lane] : 0.f;

    for (int kb = 0; kb < K; kb += 64) {
        __syncthreads();   // Wt ready (first iter) / xs reads of prev chunk done
        // stage chunk X[v0..v0+63][kb..kb+63] -> xs[k'][(i+k') & 63]
        for (int idx = t; idx < 64 * 16; idx += 256) {
            int i = idx >> 4, c = idx & 15;           // node i, float4-chunk c
            float4 val = (v0 + i < n)
                ? ((const float4*)(X + (size_t)(v0 + i) * K + kb))[c]
                : make_float4(0.f, 0.f, 0.f, 0.f);
            #pragma unroll
            for (int j = 0; j < 4; j++) {
                int kk = 4 * c + j;
                xs[kk * 64 + ((i + kk) & 63)] = (&val.x)[j];
            }
        }
        __syncthreads();
        const float* wb = &Wt[kb * 64 + j0];
        #pragma unroll 4
        for (int k = 0; k < 64; k++) {
            float xk = xs[k * 64 + ((lane + k) & 63)];
            float4 w0 = *(const float4*)&wb[k * 64 + 0];
            float4 w1 = *(const float4*)&wb[k * 64 + 4];
            float4 w2 = *(const float4*)&wb[k * 64 + 8];
            float4 w3 = *(const float4*)&wb[k * 64 + 12];
            acc[0]  = fmaf(xk, w0.x, acc[0]);  acc[1]  = fmaf(xk, w0.y, acc[1]);
            acc[2]  = fmaf(xk, w0.z, acc[2]);  acc[3]  = fmaf(xk, w0.w, acc[3]);
            acc[4]  = fmaf(xk, w1.x, acc[4]);  acc[5]  = fmaf(xk, w1.y, acc[5]);
            acc[6]  = fmaf(xk, w1.z, acc[6]);  acc[7]  = fmaf(xk, w1.w, acc[7]);
            acc[8]  = fmaf(xk, w2.x, acc[8]);  acc[9]  = fmaf(xk, w2.y, acc[9]);
            acc[10] = fmaf(xk, w2.z, acc[10]); acc[11] = fmaf(xk, w2.w, acc[11]);
            acc[12] = fmaf(xk, w3.x, acc[12]); acc[13] = fmaf(xk, w3.y, acc[13]);
            acc[14] = fmaf(xk, w3.z, acc[14]); acc[15] = fmaf(xk, w3.w, acc[15]);
        }
    }

    __syncthreads();
    // transpose via LDS (reuse xs) with rotate swizzle; store coalesced bf16 rows
    unsigned* zs32 = (unsigned*)xs;                // 64 nodes x 32 uints (2 bf16 each)
    #pragma unroll
    for (int p = 0; p < 8; p++) {
        int pl = (j0 >> 1) + p;                    // logical uint column
        int phys = (pl + lane) & 31;
        zs32[lane * 32 + phys] = pack_bf16(acc[2 * p] * dv, acc[2 * p + 1] * dv);
    }
    __syncthreads();
    for (int idx = t; idx < 2048; idx += 256) {
        int i = idx >> 5, c = idx & 31;
        int v = v0 + i;
        if (v < n) Z[(size_t)v * 32 + c] = zs32[i * 32 + ((c + i) & 31)];
    }
}

// ---------------- sparse aggregate + bias + relu (bf16 gather, full width) ----------------
// One wave per dst node; 64 lanes x 2B = one 128B line per edge. Unroll 16 for MLP.
__global__ __launch_bounds__(256) void aggregate(const ushort* __restrict__ Z,
                                                 const int* __restrict__ rowptr,
                                                 const int* __restrict__ indeg,
                                                 const int* __restrict__ csr,
                                                 const float* __restrict__ dinv,
                                                 const float* __restrict__ bias,
                                                 float* __restrict__ Xout, int n) {
    int wave = threadIdx.x >> 6;
    int lane = threadIdx.x & 63;
    int v = blockIdx.x * 4 + wave;
    if (v >= n) return;
    int vs = __builtin_amdgcn_readfirstlane(v);
    int nm1 = n - 1;

    float acc = bf16_to_f32(Z[(size_t)vs * 64 + lane]);   // self-loop
    int s = rowptr[vs], c = indeg[vs];
    int i = 0;
    for (; i + 15 < c; i += 16) {
        int idx[16];
        #pragma unroll
        for (int u = 0; u < 16; u++) idx[u] = min(csr[s + i + u], nm1);  // hardening clamp
        float a[16];
        #pragma unroll
        for (int u = 0; u < 16; u++) a[u] = bf16_to_f32(Z[(size_t)idx[u] * 64 + lane]);
        float s0 = ((a[0] + a[1]) + (a[2] + a[3])) + ((a[4] + a[5]) + (a[6] + a[7]));
        float s1 = ((a[8] + a[9]) + (a[10] + a[11])) + ((a[12] + a[13]) + (a[14] + a[15]));
        acc += s0 + s1;
    }
    for (; i + 3 < c; i += 4) {
        int i0 = min(csr[s + i], nm1),     i1 = min(csr[s + i + 1], nm1);
        int i2 = min(csr[s + i + 2], nm1), i3 = min(csr[s + i + 3], nm1);
        float a0 = bf16_to_f32(Z[(size_t)i0 * 64 + lane]);
        float a1 = bf16_to_f32(Z[(size_t)i1 * 64 + lane]);
        float a2 = bf16_to_f32(Z[(size_t)i2 * 64 + lane]);
        float a3 = bf16_to_f32(Z[(size_t)i3 * 64 + lane]);
        acc += (a0 + a1) + (a2 + a3);
    }
    for (; i < c; i++) acc += bf16_to_f32(Z[(size_t)min(csr[s + i], nm1) * 64 + lane]);

    float val = fmaxf(acc * dinv[vs] + bias[lane], 0.f);
    Xout[(size_t)vs * 64 + lane] = val;
}

// ---------------- fused pool (block per graph, batch sorted) + linear + softmax ----------------
__device__ __forceinline__ int lbound(const int* a, int n, int key) {
    int lo = 0, hi = n;
    while (lo < hi) { int mid = (lo + hi) >> 1; if (a[mid] < key) lo = mid + 1; else hi = mid; }
    return lo;
}

__global__ __launch_bounds__(256) void pool_head(const float* __restrict__ x1,
                                                 const float* __restrict__ x2,
                                                 const float* __restrict__ x3,
                                                 const int* __restrict__ batch,
                                                 const float* __restrict__ Wl,
                                                 const float* __restrict__ bl,
                                                 float* __restrict__ out, int n) {
    __shared__ int sb[2];
    __shared__ float red[4][64];
    __shared__ float ps[64];
    __shared__ float lg[10];
    int g = blockIdx.x, t = threadIdx.x;
    int wave = t >> 6, lane = t & 63;
    if (t < 2) sb[t] = lbound(batch, n, g + t);
    __syncthreads();
    int s0 = sb[0], s1 = sb[1];
    float acc = 0.f;
    for (int v = s0 + wave; v < s1; v += 4)
        acc += x1[(size_t)v * 64 + lane] + x2[(size_t)v * 64 + lane] + x3[(size_t)v * 64 + lane];
    red[wave][lane] = acc;
    __syncthreads();
    if (t < 64) {
        int c = s1 - s0;
        float denom = 3.0f * (float)(c > 1 ? c : 1);
        ps[t] = (red[0][t] + red[1][t] + red[2][t] + red[3][t]) / denom;
    }
    __syncthreads();
    if (t < 10) {
        float a = bl[t];
        #pragma unroll 8
        for (int f = 0; f < 64; f++) a += ps[f] * Wl[f * 10 + t];
        lg[t] = a;
    }
    __syncthreads();
    if (t < 10) {
        float mx = -1e30f;
        for (int j = 0; j < 10; j++) mx = fmaxf(mx, lg[j]);
        float e = expf(lg[t] - mx);
        float ss = 0.f;
        for (int j = 0; j < 10; j++) ss += expf(lg[j] - mx);
        out[g * 10 + t] = e / ss;
    }
}

extern "C" void kernel_launch(void* const* d_in, const int* in_sizes, int n_in,
                              void* d_out, int out_size, void* d_ws, size_t ws_size,
                              hipStream_t stream) {
    const float* feats = (const float*)d_in[0];
    const int*   eidx  = (const int*)d_in[1];
    const int*   batch = (const int*)d_in[2];
    const float* W1 = (const float*)d_in[4];
    const float* b1 = (const float*)d_in[5];
    const float* W2 = (const float*)d_in[6];
    const float* b2 = (const float*)d_in[7];
    const float* W3 = (const float*)d_in[8];
    const float* b3 = (const float*)d_in[9];
    const float* Wl = (const float*)d_in[10];
    const float* bl = (const float*)d_in[11];
    float* out = (float*)d_out;

    int n = in_sizes[0] / 128;
    int E = in_sizes[1] / 2;
    int G = out_size / 10;
    int NB = ((n - 1) >> 8) + 1;
    const int* row = eidx;       // destination
    const int* col = eidx + E;   // source

    char* ws = (char*)d_ws;
    size_t o = 0;
    size_t o_fill    = o; o += 2 * NBMAX * 4;           // fillR | fillC (zeroed)
    size_t o_rowptr  = o; o += ALIGN_UP((size_t)n * 4, 256);
    size_t o_indeg   = o; o += ALIGN_UP((size_t)n * 4, 256);
    size_t o_dinv    = o; o += ALIGN_UP((size_t)n * 4, 256);
    size_t o_csr     = o; o += ALIGN_UP((size_t)E * 4, 256);
    size_t o_z       = o; o += ALIGN_UP((size_t)n * 64 * 2, 256);   // bf16 Z
    size_t o_union   = o;
    size_t rb_bytes  = (size_t)NBMAX * BCAP * 4;
    size_t xl_bytes  = ALIGN_UP((size_t)n * 64 * 4, 256);
    (void)ws_size; (void)n_in;

    int*   fillR   = (int*)(ws + o_fill);
    int*   fillC   = fillR + NBMAX;
    int*   rowptr  = (int*)(ws + o_rowptr);
    int*   indeg   = (int*)(ws + o_indeg);
    float* dinv    = (float*)(ws + o_dinv);
    int*   csr     = (int*)(ws + o_csr);
    unsigned* z    = (unsigned*)(ws + o_z);
    unsigned int*  RB = (unsigned int*)(ws + o_union);
    unsigned char* CB = (unsigned char*)(ws + o_union + rb_bytes);
    float* x1 = (float*)(ws + o_union);
    float* x2 = (float*)(ws + o_union + xl_bytes);
    float* x3 = (float*)(ws + o_union + 2 * xl_bytes);

    hipMemsetAsync(ws + o_fill, 0, 2 * NBMAX * 4, stream);

    int gridG = (n + 63) / 64;   // gemm: 64 nodes per block
    int gridW = (n + 3) / 4;     // aggregate: one wave per node

    bin_edges<<<256, 1024, 0, stream>>>(row, col, E, NB, fillR, fillC, RB, CB);
    build_csr<<<NB, 1024, 0, stream>>>(RB, CB, fillR, fillC,
                                       rowptr, indeg, dinv, csr, n, NB, E);

    // conv1
    gemm_scale<128><<<gridG, 256, 0, stream>>>(feats, W1, dinv, z, n);
    aggregate<<<gridW, 256, 0, stream>>>((const ushort*)z, rowptr, indeg, csr, dinv, b1, x1, n);
    // conv2
    gemm_scale<64><<<gridG, 256, 0, stream>>>(x1, W2, dinv, z, n);
    aggregate<<<gridW, 256, 0, stream>>>((const ushort*)z, rowptr, indeg, csr, dinv, b2, x2, n);
    // conv3
    gemm_scale<64><<<gridG, 256, 0, stream>>>(x2, W3, dinv, z, n);
    aggregate<<<gridW, 256, 0, stream>>>((const ushort*)z, rowptr, indeg, csr, dinv, b3, x3, n);

    pool_head<<<G, 256, 0, stream>>>(x1, x2, x3, batch, Wl, bl, out, n);
}